// Round 1
// baseline (683.665 us; speedup 1.0000x reference)
//
#include <hip/hip_runtime.h>
#include <math.h>

#define BATCH 8
#define NN 128          // nodes
#define FS 128
#define FV 64
#define NB 8
#define HID 64
#define ROUT 320

// ---- workspace layout (float offsets) ----
#define SZ_S   (BATCH*FS*NN)        // 131072
#define SZ_V   (BATCH*FV*3*NN)      // 196608
#define SZ_T   (BATCH*FV*NN)        // 65536
#define SZ_W2T (2*ROUT*HID)         // 40960
#define OFF_SA 0
#define OFF_SB (OFF_SA+SZ_S)
#define OFF_VA (OFF_SB+SZ_S)
#define OFF_VB (OFF_VA+SZ_V)
#define OFF_T0 (OFF_VB+SZ_V)
#define OFF_T1 (OFF_T0+SZ_T)
#define OFF_W2T (OFF_T1+SZ_T)
#define OFF_COM (OFF_W2T+SZ_W2T)    // 24 floats

__device__ __forceinline__ float silu_f(float x){ return x * (1.0f/(1.0f + __expf(-x))); }

__device__ __forceinline__ float waveRed(float v){
  v += __shfl_xor(v, 32, 64);
  v += __shfl_xor(v, 16, 64);
  v += __shfl_xor(v,  8, 64);
  v += __shfl_xor(v,  4, 64);
  v += __shfl_xor(v,  2, 64);
  v += __shfl_xor(v,  1, 64);
  return v;
}

__device__ __forceinline__ float dot64(const float* hid, const float* __restrict__ w){
  float a0=0.f,a1=0.f,a2=0.f,a3=0.f;
  #pragma unroll
  for(int j=0;j<64;j+=4){
    a0 = fmaf(hid[j+0], w[j+0], a0);
    a1 = fmaf(hid[j+1], w[j+1], a1);
    a2 = fmaf(hid[j+2], w[j+2], a2);
    a3 = fmaf(hid[j+3], w[j+3], a3);
  }
  return (a0+a1)+(a2+a3);
}

// init: sA = species broadcast (transposed [b][f][n]); VA = 0; t0 = species@Wsv0
// broadcast ([b][g][n]); Wr2 transposed to [l][c][j]; com[b][3] = mean(pos)
__global__ void init_kernel(const float* __restrict__ x, const float* __restrict__ species,
                            const float* __restrict__ Wr2, const float* __restrict__ Wsv0,
                            float* __restrict__ ws)
{
  int idx = blockIdx.x*blockDim.x + threadIdx.x;
  const int total = SZ_S + SZ_V + SZ_T + SZ_W2T + 24;
  for (; idx < total; idx += gridDim.x*blockDim.x) {
    int t = idx;
    if (t < SZ_S) { int f = (t>>7)&127; ws[OFF_SA+t] = species[f]; continue; }
    t -= SZ_S;
    if (t < SZ_V) { ws[OFF_VA+t] = 0.f; continue; }
    t -= SZ_V;
    if (t < SZ_T) {
      int g = (t>>7)&63;
      float a = 0.f;
      for (int f=0; f<FS; f++) a = fmaf(species[f], Wsv0[f*FV+g], a);
      ws[OFF_T0+t] = a; continue;
    }
    t -= SZ_T;
    if (t < SZ_W2T) {
      int j = t&63; int c = (t>>6)%ROUT; int l = t/(ROUT*HID);
      ws[OFF_W2T+t] = Wr2[l*HID*ROUT + j*ROUT + c]; continue;
    }
    t -= SZ_W2T;
    { int bb=t/3, c3=t-bb*3;
      float a=0.f;
      for(int n=0;n<NN;n++) a += x[(bb*NN+n)*3+c3];
      ws[OFF_COM+t] = a*(1.0f/128.0f); }
  }
}

// one block per (batch, receiver k); 128 threads, lane = sender i
__global__ __launch_bounds__(128, 2) void layer_kernel(
    const float* __restrict__ pos,
    const float* __restrict__ sInT,   // [b][f][n]
    const float* __restrict__ vInT,   // [b][f][c3][n]
    const float* __restrict__ tInT,   // [b][g][n]
    float* __restrict__ sOutT,
    float* __restrict__ vOutT,
    float* __restrict__ tOutT,        // may be null
    const float* __restrict__ Wr1l,   // (8,64)
    const float* __restrict__ W2Tl,   // (320,64) transposed
    const float* __restrict__ WmixSl, // (192,128)
    const float* __restrict__ WmixVl, // (128,64)
    const float* __restrict__ WsvNext)// (128,64) or null
{
  const int tid  = threadIdx.x;
  const int b    = blockIdx.x >> 7;
  const int k    = blockIdx.x & 127;
  const int i    = tid;
  const int w    = tid >> 6;
  const int lane = tid & 63;

  __shared__ float aggP[2][576];
  __shared__ float aggC[576];
  __shared__ float sNew[FS];

  // ---- edge geometry (v = pos[k] - pos[i]) ----
  const float* pb = pos + b*NN*3;
  float pkx=pb[k*3+0], pky=pb[k*3+1], pkz=pb[k*3+2];
  float pix=pb[i*3+0], piy=pb[i*3+1], piz=pb[i*3+2];
  float vx=pkx-pix, vy=pky-piy, vz=pkz-piz;
  float r = sqrtf(vx*vx+vy*vy+vz*vz) + 1e-8f;
  float inv = 1.0f/r;
  float hxv=vx*inv, hyv=vy*inv, hzv=vz*inv;
  float u = r*0.2f;
  float env = 0.0f;
  if (u < 1.0f && i != k){
    float u2=u*u, u6=u2*u2*u2;
    env = 1.0f - 28.0f*u6 + 48.0f*u6*u - 21.0f*u6*u2;
  }
  float coef = 0.6324555320336759f * inv * env;   // sqrt(2/5)/r * env  (0 for self/out-of-range)
  float arg  = r * 0.6283185307179586f;           // pi*r/5

  // ---- hidden = silu(rb @ Wr1) : per-lane registers ----
  float hid[HID];
  {
    float rb[NB];
    #pragma unroll
    for(int n=0;n<NB;n++) rb[n] = coef * __sinf(arg*(float)(n+1));
    #pragma unroll
    for(int j=0;j<HID;j++) hid[j]=0.f;
    #pragma unroll
    for(int n=0;n<NB;n++){
      const float* wr = Wr1l + n*HID;
      float rn = rb[n];
      #pragma unroll
      for(int j=0;j<HID;j++) hid[j] = fmaf(rn, wr[j], hid[j]);
    }
    #pragma unroll
    for(int j=0;j<HID;j++) hid[j] = silu_f(hid[j]);
  }

  const float* sIb = sInT + b*FS*NN;
  const float* vIb = vInT + b*FV*3*NN;
  const float* tIb = tInT + b*FV*NN;

  float sk_in = sIb[tid*NN + k];   // s_in[k][tid] for epilogue

  // ---- Loop A: c in [0,128)  m0a = h * s[i,c] ----
  for (int c=0; c<FS; c+=4){
    float h0 = dot64(hid, W2Tl + (c+0)*HID);
    float h1 = dot64(hid, W2Tl + (c+1)*HID);
    float h2 = dot64(hid, W2Tl + (c+2)*HID);
    float h3 = dot64(hid, W2Tl + (c+3)*HID);
    float g0 = waveRed(h0 * sIb[(c+0)*NN+i]);
    float g1 = waveRed(h1 * sIb[(c+1)*NN+i]);
    float g2 = waveRed(h2 * sIb[(c+2)*NN+i]);
    float g3 = waveRed(h3 * sIb[(c+3)*NN+i]);
    if (lane==0){ aggP[w][c]=g0; aggP[w][c+1]=g1; aggP[w][c+2]=g2; aggP[w][c+3]=g3; }
  }
  // ---- Loop B: c in [128,192)  m0b = h * (V[i,f,:]·vhat) ----
  for (int c=FS; c<FS+FV; c+=2){
    int f = c-FS;
    float h0 = dot64(hid, W2Tl + (c+0)*HID);
    float h1 = dot64(hid, W2Tl + (c+1)*HID);
    const float* vf0 = vIb + (f+0)*3*NN;
    const float* vf1 = vIb + (f+1)*3*NN;
    float dv0 = vf0[i]*hxv + vf0[NN+i]*hyv + vf0[2*NN+i]*hzv;
    float dv1 = vf1[i]*hxv + vf1[NN+i]*hyv + vf1[2*NN+i]*hzv;
    float g0 = waveRed(h0*dv0);
    float g1 = waveRed(h1*dv1);
    if (lane==0){ aggP[w][c]=g0; aggP[w][c+1]=g1; }
  }
  // ---- Loop C1: c in [192,256)  m1a = h * t[i,f] * vhat ----
  for (int c=FS+FV; c<FS+2*FV; c++){
    int f = c-(FS+FV);
    float h = dot64(hid, W2Tl + c*HID);
    float tb = h * tIb[f*NN+i];
    float g0 = waveRed(tb*hxv);
    float g1 = waveRed(tb*hyv);
    float g2 = waveRed(tb*hzv);
    if (lane==0){ int s0=192+f*3; aggP[w][s0]=g0; aggP[w][s0+1]=g1; aggP[w][s0+2]=g2; }
  }
  // ---- Loop C2: c in [256,320)  m1b = h * V[i,f,:] ----
  for (int c=FS+2*FV; c<ROUT; c++){
    int f = c-(FS+2*FV);
    float h = dot64(hid, W2Tl + c*HID);
    const float* vf = vIb + f*3*NN;
    float g0 = waveRed(h*vf[i]);
    float g1 = waveRed(h*vf[NN+i]);
    float g2 = waveRed(h*vf[2*NN+i]);
    if (lane==0){ int s0=192+(FV+f)*3; aggP[w][s0]=g0; aggP[w][s0+1]=g1; aggP[w][s0+2]=g2; }
  }

  __syncthreads();
  for (int c=tid; c<576; c+=128) aggC[c] = (aggP[0][c]+aggP[1][c]) * (1.0f/128.0f);
  __syncthreads();

  // ---- epilogue: s update ----
  {
    float a0=0.f, a1=0.f;
    #pragma unroll 4
    for(int c=0;c<192;c+=2){
      a0 = fmaf(aggC[c],   WmixSl[c*FS+tid],     a0);
      a1 = fmaf(aggC[c+1], WmixSl[(c+1)*FS+tid], a1);
    }
    float sn = sk_in + silu_f(a0+a1);
    sNew[tid] = sn;
    sOutT[(b*FS+tid)*NN + k] = sn;
  }
  // ---- epilogue: V update ----
  for (int idx=tid; idx<192; idx+=128){
    int g = idx/3, c3 = idx-g*3;
    float a0=0.f, a1=0.f;
    #pragma unroll 4
    for(int f=0; f<128; f+=2){
      a0 = fmaf(aggC[192+f*3+c3],     WmixVl[f*FV+g],     a0);
      a1 = fmaf(aggC[192+(f+1)*3+c3], WmixVl[(f+1)*FV+g], a1);
    }
    float vin = vIb[idx*NN + k];
    vOutT[(b*FV*3 + idx)*NN + k] = vin + (a0+a1);
  }
  __syncthreads();
  // ---- epilogue: t for next layer (from updated s) ----
  if (tOutT != nullptr && tid < FV){
    float a0=0.f, a1=0.f;
    #pragma unroll 4
    for(int f=0;f<FS;f+=2){
      a0 = fmaf(sNew[f],   WsvNext[f*FV+tid],     a0);
      a1 = fmaf(sNew[f+1], WsvNext[(f+1)*FV+tid], a1);
    }
    tOutT[(b*FV+tid)*NN + k] = a0+a1;
  }
}

__global__ __launch_bounds__(128, 2) void out_kernel(
    const float* __restrict__ sT,
    const float* __restrict__ vT,
    const float* __restrict__ WoutS,
    const float* __restrict__ WoutV,
    const float* __restrict__ comv,
    float* __restrict__ out)
{
  const int tid = threadIdx.x;
  const int b = blockIdx.x >> 7;
  const int k = blockIdx.x & 127;
  __shared__ float sL[FS];
  __shared__ float vL[FV*3];
  sL[tid] = sT[(b*FS+tid)*NN + k];
  for (int idx=tid; idx<192; idx+=128) vL[idx] = vT[(b*FV*3+idx)*NN + k];
  __syncthreads();
  {
    float a0=0.f, a1=0.f;
    #pragma unroll 4
    for(int f=0;f<FS;f+=2){
      a0 = fmaf(sL[f],   WoutS[f*FS+tid],     a0);
      a1 = fmaf(sL[f+1], WoutS[(f+1)*FS+tid], a1);
    }
    out[BATCH*NN*FV*3 + (b*NN+k)*FS + tid] = a0+a1;
  }
  for (int idx=tid; idx<192; idx+=128){
    int g = idx/3, c3 = idx-g*3;
    float a = comv[b*3+c3];
    #pragma unroll 4
    for(int f=0;f<FV;f++) a = fmaf(vL[f*3+c3], WoutV[f*FV+g], a);
    out[(b*NN+k)*FV*3 + idx] = a;
  }
}

extern "C" void kernel_launch(void* const* d_in, const int* in_sizes, int n_in,
                              void* d_out, int out_size, void* d_ws, size_t ws_size,
                              hipStream_t stream)
{
  const float* x       = (const float*)d_in[0];
  const float* species = (const float*)d_in[1];
  const float* Wr1     = (const float*)d_in[2];
  const float* Wr2     = (const float*)d_in[3];
  const float* Wsv     = (const float*)d_in[4];
  const float* WmixS   = (const float*)d_in[5];
  const float* WmixV   = (const float*)d_in[6];
  const float* WoutS   = (const float*)d_in[7];
  const float* WoutV   = (const float*)d_in[8];
  float* ws  = (float*)d_ws;
  float* out = (float*)d_out;

  float* sA  = ws + OFF_SA;
  float* sB  = ws + OFF_SB;
  float* vA  = ws + OFF_VA;
  float* vB  = ws + OFF_VB;
  float* t0  = ws + OFF_T0;
  float* t1  = ws + OFF_T1;
  float* w2t = ws + OFF_W2T;
  float* com = ws + OFF_COM;

  const int initTotal = SZ_S + SZ_V + SZ_T + SZ_W2T + 24;
  init_kernel<<<(initTotal+255)/256, 256, 0, stream>>>(x, species, Wr2, Wsv, ws);

  // layer 0: reads sA/vA/t0, writes sB/vB and t1 (t for layer 1 from updated s)
  layer_kernel<<<BATCH*NN, 128, 0, stream>>>(x, sA, vA, t0, sB, vB, t1,
      Wr1,        w2t,          WmixS,           WmixV,          Wsv + FS*FV);
  // layer 1: reads sB/vB/t1, writes sA/vA
  layer_kernel<<<BATCH*NN, 128, 0, stream>>>(x, sB, vB, t1, sA, vA, nullptr,
      Wr1 + NB*HID, w2t + ROUT*HID, WmixS + 192*FS, WmixV + 128*FV, nullptr);

  out_kernel<<<BATCH*NN, 128, 0, stream>>>(sA, vA, WoutS, WoutV, com, out);
}